// Round 11
// baseline (1279.487 us; speedup 1.0000x reference)
//
#include <hip/hip_runtime.h>
#include <math.h>

// Problem constants: b=16, width=64, S=256, modes 16x16 kept (32 kx rows total).
#define TWO_PI_OVER_256 0.02454369260617026f

typedef __attribute__((ext_vector_type(8))) short short8;
typedef __attribute__((ext_vector_type(4))) float float4v;

// ---- h storage: bf16 hi/lo, MFMA-B-fragment swizzled ----------------------
// Per (b,x) row = 64KB: element (y, c, plane) at ushort offset
//   (((y>>4)*2 + (c>>5))*2 + plane)*512 + ((c>>3)&3)*128 + (y&15)*8 + (c&7)
__device__ unsigned short g_H2[(size_t)16*256*32768];  // 268 MB
__device__ float g_FY[(size_t)16*32*256*64];           // FY[b][mode32][x][c] (33.5MB)
__device__ float g_F[(size_t)32*16*64*16*2];           // F[kxi][b][i][my]{re,im}
__device__ float g_G[(size_t)16*512*64*2];             // G[b][kk512][o]{re,im}  (4MB)
__device__ float g_WT[(size_t)4*32*64*16*64*2];        // W'[blk][kxi][i][m][o]{re,im} 67MB
__device__ float g_TABT[(size_t)17*256*2];             // tabT[k][x]{cos,sin} fp32 (fwdx)
__device__ float g_TABX[(size_t)256*32*2];             // TABX[x][kxi]{cos,sin} e^{+i kx x}
__device__ unsigned short g_TBTH[256*32];              // comb B twiddle hi [y][mode]
__device__ unsigned short g_TBTL[256*32];
__device__ unsigned short g_TYF[2*2*8*64*8];           // fwd-y A-frag twiddles
__device__ unsigned short g_FC1TH[256*64];             // fc1^T bf16 hi [j][c]
__device__ unsigned short g_FC1TL[256*64];
__device__ unsigned short g_AS[(size_t)16*256*2*2048]; // A spectral frags [b][xr][pl][o][32]
__device__ unsigned short g_CWF[4*2*64*64];            // cw frags [blk][pl][o][i]

#define LPS 261   // Lp row stride in u32 (odd -> <=2-way LDS banks)

__device__ __forceinline__ int h2f_off(int y, int c, int plane) {
  return ((((y>>4)*2 + (c>>5))*2 + plane)*4 + ((c>>3)&3))*128 + (y&15)*8 + (c&7);
}

// RNE bf16 hi + truncated lo split: a ~= hi + lo with |residual| <~ 2^-17 |a|
__device__ __forceinline__ void bfsplit(float v, unsigned short& h, unsigned short& l) {
  unsigned u = __float_as_uint(v);
  unsigned r = u + 0x7FFF + ((u >> 16) & 1);
  h = (unsigned short)(r >> 16);
  float hf = __uint_as_float((unsigned)h << 16);
  l = (unsigned short)(__float_as_uint(v - hf) >> 16);
}

__device__ __forceinline__ float4v mfma16(short8 a, short8 b, float4v c) {
  return __builtin_amdgcn_mfma_f32_16x16x32_bf16(a, b, c, 0, 0, 0);
}

// async global->LDS, 16B per lane: LDS dst = base + lane*16 (HW rule),
// global src = per-lane address. Issued into vmcnt, zero VGPR cost.
__device__ __forceinline__ void gl_lds16(const unsigned short* g, unsigned short* l) {
  __builtin_amdgcn_global_load_lds(
      (const __attribute__((address_space(1))) unsigned int*)g,
      (__attribute__((address_space(3))) unsigned int*)l,
      16, 0, 0);
}

// ---------------------------------------------------------------- init tables
__global__ __launch_bounds__(256) void k_init(const float* __restrict__ fc1w,
                                              const float* __restrict__ cw) {
  int tid = blockIdx.x * blockDim.x + threadIdx.x;
  int nt  = gridDim.x * blockDim.x;
  for (int idx = tid; idx < 17*256; idx += nt) {     // fwdx twiddles (fp32)
    int k = idx >> 8, xx = idx & 255;
    int p = (k * xx) & 255;
    float a = (float)p * TWO_PI_OVER_256;
    float s, c; sincosf(a, &s, &c);
    g_TABT[idx*2] = c;  g_TABT[idx*2+1] = s;
  }
  for (int idx = tid; idx < 256*32; idx += nt) {     // invx premult: e^{+i kx x}
    int x = idx >> 5, kxi = idx & 31;
    int sx = (kxi < 16) ? kxi : kxi + 224;           // -32 mod 256 = 224
    int p = (sx * x) & 255;
    float a = (float)p * TWO_PI_OVER_256;
    float s, c; sincosf(a, &s, &c);
    g_TABX[idx*2] = c;  g_TABX[idx*2+1] = s;
  }
  for (int idx = tid; idx < 256*32; idx += nt) {     // inverse-y twiddles (comb B)
    int y = idx >> 5, kk = idx & 31, k = kk & 15;
    int p = (k * y) & 255;
    float a = (float)p * TWO_PI_OVER_256;
    float s, c; sincosf(a, &s, &c);
    float val = (kk < 16) ? c : -s;
    unsigned short h, l; bfsplit(val, h, l);
    g_TBTH[idx] = h; g_TBTL[idx] = l;
  }
  for (int idx = tid; idx < 16384; idx += nt) {      // fwd-y A-fragment twiddles
    int j = idx & 7, lane = (idx >> 3) & 63, ks = (idx >> 9) & 7;
    int mt = (idx >> 12) & 1, plane = (idx >> 13) & 1;
    int qf = lane >> 4, nf = lane & 15;
    int mode = mt*16 + nf;
    int y = ks*32 + qf*8 + j;
    int p = ((mode & 15) * y) & 255;
    float a = (float)p * TWO_PI_OVER_256;
    float s, c; sincosf(a, &s, &c);
    float val = (mode < 16) ? c : -s;                // e^{-i ky y}: Re=cos, Im=-sin
    unsigned short h, l; bfsplit(val, h, l);
    if (plane == 0) g_TYF[idx] = h; else g_TYF[idx] = l;
  }
  for (int idx = tid; idx < 64*256; idx += nt) {     // fc1_w (64,256) -> [j][c] split
    int j = idx >> 6, c = idx & 63;
    unsigned short h, l; bfsplit(fc1w[c*256 + j], h, l);
    g_FC1TH[idx] = h; g_FC1TL[idx] = l;
  }
  for (int idx = tid; idx < 4*64*64; idx += nt) {    // cw fragments [blk][pl][o][i]
    int blk = idx >> 12, o = (idx >> 6) & 63, i = idx & 63;
    unsigned short h, l; bfsplit(cw[(size_t)blk*4096 + o*64 + i], h, l);
    g_CWF[((size_t)blk*2 + 0)*4096 + o*64 + i] = h;
    g_CWF[((size_t)blk*2 + 1)*4096 + o*64 + i] = l;
  }
}

// ---------------- one-time W transpose: W'[blk][kxi][i][m][o]{re,im}
__global__ __launch_bounds__(256) void k_wt(const float* __restrict__ w1,
                                            const float* __restrict__ w2) {
  __shared__ float ls[64*34];
  int bid = blockIdx.x;
  int blk = bid >> 11, kxi = (bid >> 6) & 31, i = bid & 63;
  int t = threadIdx.x;
  int mx = kxi & 15;
  const float* wsrc = ((kxi < 16) ? w1 : w2)
                      + (size_t)blk*64*64*512 + (size_t)i*32768 + mx*32;
  int o = t >> 2, part = t & 3;
  float4 v0 = *(const float4*)(wsrc + o*512 + part*8);
  float4 v1 = *(const float4*)(wsrc + o*512 + part*8 + 4);
  *(float4*)&ls[o*34 + part*8] = v0;
  *(float4*)&ls[o*34 + part*8 + 4] = v1;
  __syncthreads();
  float* outp = g_WT + (((size_t)blk*32 + kxi)*64 + i)*2048;
  float vals[8];
  #pragma unroll
  for (int j = 0; j < 8; ++j) {
    int idx = t*8 + j;
    int mm = idx >> 7, rem = idx & 127, o2 = rem >> 1, c = rem & 1;
    vals[j] = ls[o2*34 + mm*2 + c];
  }
  *(float4*)&outp[t*8]     = make_float4(vals[0], vals[1], vals[2], vals[3]);
  *(float4*)&outp[t*8 + 4] = make_float4(vals[4], vals[5], vals[6], vals[7]);
}

// ------------- lift (fc0) + FUSED forward y-DFT (single-barrier epilogue)
// b0: batch-half offset (grid 2048 = 8 b x 256 xr)
__global__ __launch_bounds__(256) void k_lift(const float* __restrict__ x,
                                              const float* __restrict__ w,
                                              const float* __restrict__ bias,
                                              int b0) {
  __shared__ unsigned Lp[64*LPS];     // 66.8 KB packed (hi|lo) h row [c][y]
  int b = b0 + (blockIdx.x >> 8), xr = blockIdx.x & 255, t = threadIdx.x;  // t = y
  const float* xp = x + ((size_t)(b*256 + xr) * 256) * 3;
  float x0 = xp[t*3], x1 = xp[t*3+1], x2 = xp[t*3+2];
  unsigned short* row = g_H2 + (size_t)(b*256 + xr) * 32768;
  float v[64];
  #pragma unroll
  for (int c = 0; c < 64; ++c)
    v[c] = bias[c] + x0*w[c] + x1*w[64+c] + x2*w[128+c];
  #pragma unroll
  for (int ktc = 0; ktc < 2; ++ktc)
    #pragma unroll
    for (int q8 = 0; q8 < 4; ++q8) {
      short8 hi, lo;
      #pragma unroll
      for (int j = 0; j < 8; ++j) {
        int c = ktc*32 + q8*8 + j;
        unsigned short h, l; bfsplit(v[c], h, l);
        hi[j] = (short)h; lo[j] = (short)l;
        Lp[c*LPS + t] = ((unsigned)h << 16) | l;
      }
      *(short8*)&row[h2f_off(t, ktc*32 + q8*8, 0)] = hi;
      *(short8*)&row[h2f_off(t, ktc*32 + q8*8, 1)] = lo;
    }
  __syncthreads();

  int wv = t >> 6, lane = t & 63, q = lane >> 4, n = lane & 15;
  const float inv = 1.f/65536.f;
  {
    int pf = wv;                              // this wave's c-chunk
    float4v a2[2]; a2[0] = (float4v)(0.f); a2[1] = (float4v)(0.f);
    #pragma unroll
    for (int kg = 0; kg < 8; ++kg) {          // all 8 y-chunks
      short8 bh, bl;
      #pragma unroll
      for (int j = 0; j < 8; ++j) {
        unsigned pv = Lp[(pf*16 + n)*LPS + kg*32 + q*8 + j];
        bh[j] = (short)(pv >> 16); bl[j] = (short)(pv & 0xffffu);
      }
      #pragma unroll
      for (int mt2 = 0; mt2 < 2; ++mt2) {
        short8 ah = *(const short8*)&g_TYF[((0*2 + mt2)*8 + kg)*512 + lane*8];
        short8 al = *(const short8*)&g_TYF[((2 + mt2)*8 + kg)*512 + lane*8];
        a2[mt2] = mfma16(ah, bh, a2[mt2]);
        a2[mt2] = mfma16(ah, bl, a2[mt2]);
        a2[mt2] = mfma16(al, bh, a2[mt2]);
      }
    }
    #pragma unroll
    for (int mt2 = 0; mt2 < 2; ++mt2)
      #pragma unroll
      for (int r = 0; r < 4; ++r) {
        int mode = mt2*16 + q*4 + r;
        g_FY[((size_t)(b*32 + mode)*256 + xr)*64 + pf*16 + n] = a2[mt2][r] * inv;
      }
  }
}

// ------------------- forward x-DFT from FY -> F.  grid 1024: (b8, cg8, ky16)
__global__ __launch_bounds__(256) void k_fwdx(int b0) {
  __shared__ float fr[256*8], fi[256*8];
  int bid = blockIdx.x;
  int b = b0 + (bid >> 7), cg = (bid >> 4) & 7, ky = bid & 15;
  int t = threadIdx.x, kxi = t >> 3, cl = t & 7;
  int kt = (kxi < 16) ? kxi : 32 - kxi;
  float sgn = (kxi < 16) ? -1.f : 1.f;         // e^{-i kx x} = (c, sgn*s)
  {
    int u0 = t, x0 = u0 >> 1, p0 = u0 & 1;
    int u1 = t + 256, x1 = u1 >> 1, p1 = u1 & 1;
    const float* fyr = g_FY + ((size_t)(b*32 + ky)*256)*64 + cg*8;
    const float* fyi = g_FY + ((size_t)(b*32 + 16 + ky)*256)*64 + cg*8;
    *(float4*)&fr[x0*8 + p0*4] = *(const float4*)&fyr[(size_t)x0*64 + p0*4];
    *(float4*)&fr[x1*8 + p1*4] = *(const float4*)&fyr[(size_t)x1*64 + p1*4];
    *(float4*)&fi[x0*8 + p0*4] = *(const float4*)&fyi[(size_t)x0*64 + p0*4];
    *(float4*)&fi[x1*8 + p1*4] = *(const float4*)&fyi[(size_t)x1*64 + p1*4];
  }
  __syncthreads();
  float r0 = 0.f, r1 = 0.f, i0 = 0.f, i1 = 0.f;
  #pragma unroll 2
  for (int x = 0; x < 256; x += 2) {
    float2 tw0 = ((const float2*)g_TABT)[kt*256 + x];
    float2 tw1 = ((const float2*)g_TABT)[kt*256 + x + 1];
    float a0 = fr[x*8 + cl], b0v = fi[x*8 + cl];
    float a1 = fr[(x+1)*8 + cl], b1v = fi[(x+1)*8 + cl];
    float es0 = sgn*tw0.y, es1 = sgn*tw1.y;
    r0 += a0*tw0.x - b0v*es0;  i0 += a0*es0 + b0v*tw0.x;
    r1 += a1*tw1.x - b1v*es1;  i1 += a1*es1 + b1v*tw1.x;
  }
  ((float2*)g_F)[((size_t)(kxi*16 + b)*64 + cg*8 + cl)*16 + ky] =
    make_float2(r0 + r1, i0 + i1);
}

// ---------------------------------------------------- spectral channel mix
// mix3: W-row register reuse. grid 128 (kxi 32, bqh 2, mh 2); bq = bq0 + bqh.
__global__ __launch_bounds__(256) void k_mix3(int blk, int bq0) {
  __shared__ float2 Lr[4*4*8*64];    // [w][b][m][o] 64KB
  int bid = blockIdx.x;
  int kxi = bid >> 2, bq = bq0 + ((bid >> 1) & 1), mh = bid & 1;
  int t = threadIdx.x;
  int o = t & 63;
  int w = __builtin_amdgcn_readfirstlane((int)(t >> 6));
  const float2* Wp = (const float2*)g_WT + (((size_t)blk*32 + kxi)*64)*1024 + mh*8*64 + o;
  const float2* Fb = (const float2*)g_F + ((size_t)kxi*16 + bq*4)*64*16 + mh*8;

  float gr[4][8], gi[4][8];
  #pragma unroll
  for (int b = 0; b < 4; ++b)
    #pragma unroll
    for (int m = 0; m < 8; ++m) { gr[b][m] = 0.f; gi[b][m] = 0.f; }

  for (int il = 0; il < 16; ++il) {
    int i = w*16 + il;
    const float2* wrow = Wp + (size_t)i*1024;       // [m][o]
    float2 wv[8];
    #pragma unroll
    for (int m = 0; m < 8; ++m) wv[m] = wrow[(size_t)m*64];
    #pragma unroll
    for (int b = 0; b < 4; ++b) {
      const float2* fr2 = Fb + ((size_t)b*64 + i)*16;  // uniform -> s_load
      #pragma unroll
      for (int m = 0; m < 8; ++m) {
        float2 f = fr2[m];
        gr[b][m] += f.x*wv[m].x - f.y*wv[m].y;
        gi[b][m] += f.x*wv[m].y + f.y*wv[m].x;
      }
    }
  }
  #pragma unroll
  for (int b = 0; b < 4; ++b)
    #pragma unroll
    for (int m = 0; m < 8; ++m)
      Lr[((w*4 + b)*8 + m)*64 + o] = make_float2(gr[b][m], gi[b][m]);
  __syncthreads();
  for (int e = t; e < 2048; e += 256) {
    int oo = e & 63, m = (e >> 6) & 7, b = e >> 9;
    float2 s0 = Lr[((0*4 + b)*8 + m)*64 + oo];
    float2 s1 = Lr[((1*4 + b)*8 + m)*64 + oo];
    float2 s2 = Lr[((2*4 + b)*8 + m)*64 + oo];
    float2 s3 = Lr[((3*4 + b)*8 + m)*64 + oo];
    float2 g = make_float2((s0.x + s1.x) + (s2.x + s3.x),
                           (s0.y + s1.y) + (s2.y + s3.y));
    ((float2*)g_G)[((size_t)(bq*4 + b)*512 + kxi*16 + mh*8 + m)*64 + oo] = g;
  }
}

// ------------------- inverse-x DFT hoisted out of combine.
// grid 256: (b 8, xc 32), 512 threads; each block does 8 xr rows.
__global__ __launch_bounds__(512) void k_invx(int b0) {
  __shared__ float2 Tw[256];        // 8 xr x 32 kxi twiddles
  __shared__ float  Tr[8*64*33];    // 67.6 KB: all 8 xr transposes at once
  int bid = blockIdx.x;
  int b = b0 + (bid >> 5), xc = bid & 31;
  int t = threadIdx.x;
  if (t < 256) Tw[t] = ((const float2*)g_TABX)[(size_t)(xc*8)*32 + t];
  int o2 = t & 31, k = t >> 5;       // o = 2*o2, 2*o2+1 ; k = 0..15
  const float4* Gb4 = (const float4*)g_G + (size_t)b*512*32;
  float4 acc[8];
  #pragma unroll
  for (int r = 0; r < 8; ++r) acc[r] = make_float4(0.f, 0.f, 0.f, 0.f);
  __syncthreads();
  for (int kxi = 0; kxi < 32; ++kxi) {
    float4 g = Gb4[(size_t)(kxi*16 + k)*32 + o2];
    #pragma unroll
    for (int r = 0; r < 8; ++r) {
      float2 tw = Tw[r*32 + kxi];
      acc[r].x += g.x*tw.x - g.y*tw.y;
      acc[r].y += g.x*tw.y + g.y*tw.x;
      acc[r].z += g.z*tw.x - g.w*tw.y;
      acc[r].w += g.z*tw.y + g.w*tw.x;
    }
  }
  float wk = k ? 2.f : 1.f;                    // irfft: ky=0 once, others x2
  #pragma unroll
  for (int r = 0; r < 8; ++r) {
    float* Trr = &Tr[r*2112];
    Trr[(2*o2)*33 + k]        = wk*acc[r].x;   // re -> col k
    Trr[(2*o2)*33 + 16 + k]   = wk*acc[r].y;   // im -> col 16+k
    Trr[(2*o2+1)*33 + k]      = wk*acc[r].z;
    Trr[(2*o2+1)*33 + 16 + k] = wk*acc[r].w;
  }
  __syncthreads();
  int o = t >> 3, c0 = (t & 7)*4;
  #pragma unroll
  for (int r = 0; r < 8; ++r) {
    unsigned long long hv = 0, lv = 0;
    #pragma unroll
    for (int j = 0; j < 4; ++j) {
      unsigned short h, l; bfsplit(Tr[r*2112 + o*33 + c0 + j], h, l);
      hv |= (unsigned long long)h << (16*j);
      lv |= (unsigned long long)l << (16*j);
    }
    unsigned short* dst = g_AS + (size_t)(b*256 + xc*8 + r)*4096 + o*32 + c0;
    *(unsigned long long*)&dst[0]    = hv;     // hi plane
    *(unsigned long long*)&dst[2048] = lv;     // lo plane
  }
}

// ------------------- combine (blk 0..2): C(64o x 256y) = A(64x96) B(96x256)
// 512 threads / 8 waves; wave (yq, oh) owns 64y x 32o tile. grid 2048 (b8,xr256).
// R6 structure (best verified): full 64KB pool staged once under kt0,
// single-phase epilogue (full 64-row Lp aliasing dead pool), per-wave fy.
__global__ __launch_bounds__(512, 4) void k_comb(int blk, const float* __restrict__ cb,
                                                 int b0) {
  __shared__ unsigned Lp[64*LPS];               // 66.8 KB; first 64KB = stage pool
  unsigned short* pool = (unsigned short*)Lp;
  int b = b0 + (blockIdx.x >> 8), xr = blockIdx.x & 255;
  int t = threadIdx.x;
  unsigned short* row = g_H2 + (size_t)(b*256 + xr) * 32768;
  int w = t >> 6, lane = t & 63, q = lane >> 4, n = lane & 15;
  int yq = w >> 1, oh = w & 1;
  int ybase = yq*64;
  const unsigned short* Ab = g_AS + (size_t)(b*256 + xr)*4096;
  const unsigned short* Cw = g_CWF + (size_t)blk*8192;

  float4v acc[4][2];
  #pragma unroll
  for (int nt = 0; nt < 4; ++nt)
    #pragma unroll
    for (int mtl = 0; mtl < 2; ++mtl) acc[nt][mtl] = (float4v)(0.f);

  // kt0 + cw register loads first (their wait leaves staging in flight)
  short8 af0[2][2], af1[2][2], af2[2][2], b0h[4], b0l[4];
  #pragma unroll
  for (int mtl = 0; mtl < 2; ++mtl) {
    int o = (oh*2 + mtl)*16 + n;
    af0[mtl][0] = *(const short8*)&Ab[o*32 + q*8];
    af0[mtl][1] = *(const short8*)&Ab[2048 + o*32 + q*8];
    af1[mtl][0] = *(const short8*)&Cw[o*64 + q*8];
    af1[mtl][1] = *(const short8*)&Cw[4096 + o*64 + q*8];
    af2[mtl][0] = *(const short8*)&Cw[o*64 + 32 + q*8];
    af2[mtl][1] = *(const short8*)&Cw[4096 + o*64 + 32 + q*8];
  }
  #pragma unroll
  for (int nt = 0; nt < 4; ++nt) {
    int y = ybase + nt*16 + n;
    b0h[nt] = *(const short8*)&g_TBTH[y*32 + q*8];
    b0l[nt] = *(const short8*)&g_TBTL[y*32 + q*8];
  }
  // async-stage the full H2 row: wave w -> stripes 8w..8w+7 (1KB each)
  #pragma unroll
  for (int i = 0; i < 8; ++i) {
    int s = w*8 + i;
    gl_lds16(row + s*512 + lane*8, &pool[s*512]);
  }
  // kt0 compute (staged loads still in flight behind it)
  #pragma unroll
  for (int nt = 0; nt < 4; ++nt)
    #pragma unroll
    for (int mtl = 0; mtl < 2; ++mtl) {
      acc[nt][mtl] = mfma16(af0[mtl][0], b0h[nt], acc[nt][mtl]);
      acc[nt][mtl] = mfma16(af0[mtl][0], b0l[nt], acc[nt][mtl]);
      acc[nt][mtl] = mfma16(af0[mtl][1], b0h[nt], acc[nt][mtl]);
    }
  __syncthreads();   // drains vmcnt: all 64 stripes resident in LDS

  // kt1/kt2 B-fragments from LDS: stripe = ytile*4 + (kt-1)*2 + plane
  #pragma unroll
  for (int nt = 0; nt < 4; ++nt) {
    int sb = (yq*4 + nt)*4;
    short8 p1h = *(const short8*)&pool[(sb + 0)*512 + lane*8];
    short8 p1l = *(const short8*)&pool[(sb + 1)*512 + lane*8];
    short8 p2h = *(const short8*)&pool[(sb + 2)*512 + lane*8];
    short8 p2l = *(const short8*)&pool[(sb + 3)*512 + lane*8];
    #pragma unroll
    for (int mtl = 0; mtl < 2; ++mtl) {
      acc[nt][mtl] = mfma16(af1[mtl][0], p1h, acc[nt][mtl]);
      acc[nt][mtl] = mfma16(af1[mtl][0], p1l, acc[nt][mtl]);
      acc[nt][mtl] = mfma16(af1[mtl][1], p1h, acc[nt][mtl]);
      acc[nt][mtl] = mfma16(af2[mtl][0], p2h, acc[nt][mtl]);
      acc[nt][mtl] = mfma16(af2[mtl][0], p2l, acc[nt][mtl]);
      acc[nt][mtl] = mfma16(af2[mtl][1], p2h, acc[nt][mtl]);
    }
  }
  __syncthreads();   // all pool reads done; pool dead -> Lp may overwrite

  // ---- single-phase epilogue: relu+bias+pack; full Lp + direct H2F stores
  #pragma unroll
  for (int mtl = 0; mtl < 2; ++mtl) {
    int p = oh*2 + mtl;
    float4v cbv = *(const float4v*)(cb + p*16 + q*4);
    #pragma unroll
    for (int nt = 0; nt < 4; ++nt) {
      int y = ybase + nt*16 + n;
      unsigned long long hh = 0, ll = 0;
      #pragma unroll
      for (int r = 0; r < 4; ++r) {
        float v = fmaxf(acc[nt][mtl][r] + cbv[r], 0.f);
        unsigned short h, l; bfsplit(v, h, l);
        hh |= (unsigned long long)h << (r*16);
        ll |= (unsigned long long)l << (r*16);
        Lp[(p*16 + q*4 + r)*LPS + y] = ((unsigned)h << 16) | l;
      }
      int off0 = (((yq*4 + nt)*2 + (p>>1))*2 + 0)*512
               + (2*(p&1) + (q>>1))*128 + n*8 + 4*(q&1);
      *(unsigned long long*)&row[off0]       = hh;
      *(unsigned long long*)&row[off0 + 512] = ll;
    }
  }
  __syncthreads();                              // Lp complete

  // ---- fy DFT: wave w owns (mt2 = w&1, c-chunk pf = w>>1); 24 MFMAs, no reduce
  {
    const float inv = 1.f/65536.f;
    int mt2 = w & 1, pf = w >> 1;
    float4v a2 = (float4v)(0.f);
    #pragma unroll
    for (int kg = 0; kg < 8; ++kg) {
      short8 bh, bl;
      #pragma unroll
      for (int j = 0; j < 8; ++j) {
        unsigned pv = Lp[(pf*16 + n)*LPS + kg*32 + q*8 + j];
        bh[j] = (short)(pv >> 16); bl[j] = (short)(pv & 0xffffu);
      }
      short8 ah = *(const short8*)&g_TYF[((0*2 + mt2)*8 + kg)*512 + lane*8];
      short8 al = *(const short8*)&g_TYF[((2 + mt2)*8 + kg)*512 + lane*8];
      a2 = mfma16(ah, bh, a2);
      a2 = mfma16(ah, bl, a2);
      a2 = mfma16(al, bh, a2);
    }
    #pragma unroll
    for (int r = 0; r < 4; ++r) {
      int mode = mt2*16 + q*4 + r;
      g_FY[((size_t)(b*32 + mode)*256 + xr)*64 + pf*16 + n] = a2[r] * inv;
    }
  }
}

// ------------------- combine blk 3 + FUSED head. grid 2048 (b8,xr256).
__global__ __launch_bounds__(512, 4) void k_combh(const float* __restrict__ cb,
                                               const float* __restrict__ fc1b,
                                               const float* __restrict__ fc2w,
                                               const float* __restrict__ fc2b,
                                               float* __restrict__ out,
                                               int b0) {
  __shared__ unsigned Lp[64*LPS];               // 66.8 KB; first 64KB = stage pool
  unsigned short* pool = (unsigned short*)Lp;
  int b = b0 + (blockIdx.x >> 8), xr = blockIdx.x & 255;
  int t = threadIdx.x;
  unsigned short* row = g_H2 + (size_t)(b*256 + xr) * 32768;
  int w = t >> 6, lane = t & 63, q = lane >> 4, n = lane & 15;
  int yq = w >> 1, oh = w & 1;
  int ybase = yq*64;
  const unsigned short* Ab = g_AS + (size_t)(b*256 + xr)*4096;
  const unsigned short* Cw = g_CWF + (size_t)3*8192;

  float4v acc[4][2];
  #pragma unroll
  for (int nt = 0; nt < 4; ++nt)
    #pragma unroll
    for (int mtl = 0; mtl < 2; ++mtl) acc[nt][mtl] = (float4v)(0.f);

  short8 af0[2][2], af1[2][2], af2[2][2], b0h[4], b0l[4];
  #pragma unroll
  for (int mtl = 0; mtl < 2; ++mtl) {
    int o = (oh*2 + mtl)*16 + n;
    af0[mtl][0] = *(const short8*)&Ab[o*32 + q*8];
    af0[mtl][1] = *(const short8*)&Ab[2048 + o*32 + q*8];
    af1[mtl][0] = *(const short8*)&Cw[o*64 + q*8];
    af1[mtl][1] = *(const short8*)&Cw[4096 + o*64 + q*8];
    af2[mtl][0] = *(const short8*)&Cw[o*64 + 32 + q*8];
    af2[mtl][1] = *(const short8*)&Cw[4096 + o*64 + 32 + q*8];
  }
  #pragma unroll
  for (int nt = 0; nt < 4; ++nt) {
    int y = ybase + nt*16 + n;
    b0h[nt] = *(const short8*)&g_TBTH[y*32 + q*8];
    b0l[nt] = *(const short8*)&g_TBTL[y*32 + q*8];
  }
  #pragma unroll
  for (int i = 0; i < 8; ++i) {
    int s = w*8 + i;
    gl_lds16(row + s*512 + lane*8, &pool[s*512]);
  }
  #pragma unroll
  for (int nt = 0; nt < 4; ++nt)
    #pragma unroll
    for (int mtl = 0; mtl < 2; ++mtl) {
      acc[nt][mtl] = mfma16(af0[mtl][0], b0h[nt], acc[nt][mtl]);
      acc[nt][mtl] = mfma16(af0[mtl][0], b0l[nt], acc[nt][mtl]);
      acc[nt][mtl] = mfma16(af0[mtl][1], b0h[nt], acc[nt][mtl]);
    }
  __syncthreads();   // stage resident

  #pragma unroll
  for (int nt = 0; nt < 4; ++nt) {
    int sb = (yq*4 + nt)*4;
    short8 p1h = *(const short8*)&pool[(sb + 0)*512 + lane*8];
    short8 p1l = *(const short8*)&pool[(sb + 1)*512 + lane*8];
    short8 p2h = *(const short8*)&pool[(sb + 2)*512 + lane*8];
    short8 p2l = *(const short8*)&pool[(sb + 3)*512 + lane*8];
    #pragma unroll
    for (int mtl = 0; mtl < 2; ++mtl) {
      acc[nt][mtl] = mfma16(af1[mtl][0], p1h, acc[nt][mtl]);
      acc[nt][mtl] = mfma16(af1[mtl][0], p1l, acc[nt][mtl]);
      acc[nt][mtl] = mfma16(af1[mtl][1], p1h, acc[nt][mtl]);
      acc[nt][mtl] = mfma16(af2[mtl][0], p2h, acc[nt][mtl]);
      acc[nt][mtl] = mfma16(af2[mtl][0], p2l, acc[nt][mtl]);
      acc[nt][mtl] = mfma16(af2[mtl][1], p2h, acc[nt][mtl]);
    }
  }
  __syncthreads();   // pool reads done; pool dead -> Lp may overwrite

  // ---- single-phase Lp write: h (+cb, NO relu) for all channels
  #pragma unroll
  for (int mtl = 0; mtl < 2; ++mtl) {
    int p = oh*2 + mtl;
    float4v cbv = *(const float4v*)(cb + p*16 + q*4);
    #pragma unroll
    for (int nt = 0; nt < 4; ++nt) {
      int y = ybase + nt*16 + n;
      #pragma unroll
      for (int r = 0; r < 4; ++r) {
        float v = acc[nt][mtl][r] + cbv[r];
        unsigned short h, l; bfsplit(v, h, l);
        Lp[(p*16 + q*4 + r)*LPS + y] = ((unsigned)h << 16) | l;
      }
    }
  }
  __syncthreads();                              // Lp complete

  // ---- captures from full Lp (c = q*8+j and 32 + q*8+j)
  short8 B0h[4], B0l[4], B1h[4], B1l[4];
  #pragma unroll
  for (int ntl = 0; ntl < 4; ++ntl) {
    int y = ybase + ntl*16 + n;
    #pragma unroll
    for (int j = 0; j < 8; ++j) {
      unsigned pv0 = Lp[(q*8 + j)*LPS + y];
      B0h[ntl][j] = (short)(pv0 >> 16); B0l[ntl][j] = (short)(pv0 & 0xffffu);
      unsigned pv1 = Lp[(32 + q*8 + j)*LPS + y];
      B1h[ntl][j] = (short)(pv1 >> 16); B1l[ntl][j] = (short)(pv1 & 0xffffu);
    }
  }

  // ---- head GEMM: this wave's j-half (oh), from captured fragments
  float outp[4] = {0.f, 0.f, 0.f, 0.f};
  #pragma unroll 2
  for (int mti = 0; mti < 8; ++mti) {
    int mt = oh*8 + mti;
    int jrow = mt*16 + n;
    short8 a0h = *(const short8*)&g_FC1TH[jrow*64 + q*8];
    short8 a0l = *(const short8*)&g_FC1TL[jrow*64 + q*8];
    short8 a1h = *(const short8*)&g_FC1TH[jrow*64 + 32 + q*8];
    short8 a1l = *(const short8*)&g_FC1TL[jrow*64 + 32 + q*8];
    float4v ac2[4];
    #pragma unroll
    for (int ntl = 0; ntl < 4; ++ntl) ac2[ntl] = (float4v)(0.f);
    #pragma unroll
    for (int ntl = 0; ntl < 4; ++ntl) {
      ac2[ntl] = mfma16(a0h, B0h[ntl], ac2[ntl]);
      ac2[ntl] = mfma16(a0h, B0l[ntl], ac2[ntl]);
      ac2[ntl] = mfma16(a0l, B0h[ntl], ac2[ntl]);
      ac2[ntl] = mfma16(a1h, B1h[ntl], ac2[ntl]);
      ac2[ntl] = mfma16(a1h, B1l[ntl], ac2[ntl]);
      ac2[ntl] = mfma16(a1l, B1h[ntl], ac2[ntl]);
    }
    float4v b1 = *(const float4v*)(fc1b + mt*16 + q*4);
    float4v w2 = *(const float4v*)(fc2w + mt*16 + q*4);
    #pragma unroll
    for (int ntl = 0; ntl < 4; ++ntl)
      #pragma unroll
      for (int r = 0; r < 4; ++r)
        outp[ntl] += w2[r] * fmaxf(ac2[ntl][r] + b1[r], 0.f);
  }

  // intra-wave j-reduce (over q), then cross-wave (oh pair) via LDS
  float vv[4];
  #pragma unroll
  for (int ntl = 0; ntl < 4; ++ntl) {
    float v = outp[ntl];
    v += __shfl_xor(v, 16);
    v += __shfl_xor(v, 32);
    vv[ntl] = v;
  }
  float* Ored = (float*)Lp;                     // reuse LDS (captures done)
  __syncthreads();
  if (oh == 0 && q == 0) {
    #pragma unroll
    for (int ntl = 0; ntl < 4; ++ntl)
      Ored[ybase + ntl*16 + n] = vv[ntl];
  }
  __syncthreads();
  if (oh == 1 && q == 0) {
    float bias2 = fc2b[0];
    #pragma unroll
    for (int ntl = 0; ntl < 4; ++ntl) {
      int y = ybase + ntl*16 + n;
      out[((size_t)(b*256 + xr))*256 + y] = Ored[y] + vv[ntl] + bias2;
    }
  }
}

// ----------------------------------------------------------------- launcher
// Batch-halved pipeline: run lift + all 4 layers for b in [0,8), then [8,16).
// Working set per half (~180 MB: H2-half 134 + FY 17 + W'blk 17 + AS 8 + G 2)
// fits the 256 MB L3 -> the combines' H2 reads become L3 hits.
extern "C" void kernel_launch(void* const* d_in, const int* in_sizes, int n_in,
                              void* d_out, int out_size, void* d_ws, size_t ws_size,
                              hipStream_t stream) {
  (void)in_sizes; (void)n_in; (void)out_size; (void)d_ws; (void)ws_size;
  const float* x    = (const float*)d_in[0];
  const float* fc0w = (const float*)d_in[1];
  const float* fc0b = (const float*)d_in[2];
  const float* w1   = (const float*)d_in[3];
  const float* w2   = (const float*)d_in[4];
  const float* cw   = (const float*)d_in[5];
  const float* cb   = (const float*)d_in[6];
  const float* fc1w = (const float*)d_in[7];
  const float* fc1b = (const float*)d_in[8];
  const float* fc2w = (const float*)d_in[9];
  const float* fc2b = (const float*)d_in[10];
  float* out = (float*)d_out;

  hipLaunchKernelGGL(k_init, dim3(64),   dim3(256), 0, stream, fc1w, cw);
  hipLaunchKernelGGL(k_wt,   dim3(8192), dim3(256), 0, stream, w1, w2);
  for (int half = 0; half < 2; ++half) {
    int b0 = half * 8, bq0 = half * 2;
    hipLaunchKernelGGL(k_lift, dim3(2048), dim3(256), 0, stream, x, fc0w, fc0b, b0);
    for (int blk = 0; blk < 3; ++blk) {
      hipLaunchKernelGGL(k_fwdx, dim3(1024), dim3(256), 0, stream, b0);
      hipLaunchKernelGGL(k_mix3, dim3(128),  dim3(256), 0, stream, blk, bq0);
      hipLaunchKernelGGL(k_invx, dim3(256),  dim3(512), 0, stream, b0);
      hipLaunchKernelGGL(k_comb, dim3(2048), dim3(512), 0, stream,
                         blk, cb + (size_t)blk*64, b0);
    }
    hipLaunchKernelGGL(k_fwdx, dim3(1024), dim3(256), 0, stream, b0);
    hipLaunchKernelGGL(k_mix3, dim3(128),  dim3(256), 0, stream, 3, bq0);
    hipLaunchKernelGGL(k_invx, dim3(256),  dim3(512), 0, stream, b0);
    hipLaunchKernelGGL(k_combh, dim3(2048), dim3(512), 0, stream,
                       cb + (size_t)3*64, fc1b, fc2w, fc2b, out, b0);
  }
}

// Round 12
// 1251.545 us; speedup vs baseline: 1.0223x; 1.0223x over previous
//
#include <hip/hip_runtime.h>
#include <math.h>

// Problem constants: b=16, width=64, S=256, modes 16x16 kept (32 kx rows total).
#define TWO_PI_OVER_256 0.02454369260617026f

typedef __attribute__((ext_vector_type(8))) short short8;
typedef __attribute__((ext_vector_type(4))) float float4v;

// ---- h storage: bf16 hi/lo, MFMA-B-fragment swizzled ----------------------
// Per (b,x) row = 64KB: element (y, c, plane) at ushort offset
//   (((y>>4)*2 + (c>>5))*2 + plane)*512 + ((c>>3)&3)*128 + (y&15)*8 + (c&7)
__device__ unsigned short g_H2[(size_t)16*256*32768];  // 268 MB
__device__ float g_FY[(size_t)16*32*256*64];           // FY[b][mode32][x][c] (33.5MB)
__device__ float g_F[(size_t)32*16*64*16*2];           // F[kxi][b][i][my]{re,im}
__device__ float g_G[(size_t)16*512*64*2];             // G[b][kk512][o]{re,im}  (4MB)
__device__ float g_WT[(size_t)4*32*64*16*64*2];        // W'[blk][kxi][i][m][o]{re,im} 67MB
__device__ float g_TABT[(size_t)17*256*2];             // tabT[k][x]{cos,sin} fp32 (fwdx)
__device__ float g_TABX[(size_t)256*32*2];             // TABX[x][kxi]{cos,sin} e^{+i kx x}
__device__ unsigned short g_TBTH[256*32];              // comb B twiddle hi [y][mode]
__device__ unsigned short g_TBTL[256*32];
__device__ unsigned short g_TYF[2*2*8*64*8];           // fwd-y A-frag twiddles
__device__ unsigned short g_FC1TH[256*64];             // fc1^T bf16 hi [j][c]
__device__ unsigned short g_FC1TL[256*64];
__device__ unsigned short g_AS[(size_t)16*256*2*2048]; // A spectral frags [b][xr][pl][o][32]
__device__ unsigned short g_CWF[4*2*64*64];            // cw frags [blk][pl][o][i]

#define LPS 261   // Lp row stride in u32 (odd -> <=2-way LDS banks)

__device__ __forceinline__ int h2f_off(int y, int c, int plane) {
  return ((((y>>4)*2 + (c>>5))*2 + plane)*4 + ((c>>3)&3))*128 + (y&15)*8 + (c&7);
}

// RNE bf16 hi + truncated lo split: a ~= hi + lo with |residual| <~ 2^-17 |a|
__device__ __forceinline__ void bfsplit(float v, unsigned short& h, unsigned short& l) {
  unsigned u = __float_as_uint(v);
  unsigned r = u + 0x7FFF + ((u >> 16) & 1);
  h = (unsigned short)(r >> 16);
  float hf = __uint_as_float((unsigned)h << 16);
  l = (unsigned short)(__float_as_uint(v - hf) >> 16);
}

__device__ __forceinline__ float4v mfma16(short8 a, short8 b, float4v c) {
  return __builtin_amdgcn_mfma_f32_16x16x32_bf16(a, b, c, 0, 0, 0);
}

// async global->LDS, 16B per lane: LDS dst = base + lane*16 (HW rule),
// global src = per-lane address. Issued into vmcnt, zero VGPR cost.
__device__ __forceinline__ void gl_lds16(const unsigned short* g, unsigned short* l) {
  __builtin_amdgcn_global_load_lds(
      (const __attribute__((address_space(1))) unsigned int*)g,
      (__attribute__((address_space(3))) unsigned int*)l,
      16, 0, 0);
}

// ---------------------------------------------------------------- init tables
__global__ __launch_bounds__(256) void k_init(const float* __restrict__ fc1w,
                                              const float* __restrict__ cw) {
  int tid = blockIdx.x * blockDim.x + threadIdx.x;
  int nt  = gridDim.x * blockDim.x;
  for (int idx = tid; idx < 17*256; idx += nt) {     // fwdx twiddles (fp32)
    int k = idx >> 8, xx = idx & 255;
    int p = (k * xx) & 255;
    float a = (float)p * TWO_PI_OVER_256;
    float s, c; sincosf(a, &s, &c);
    g_TABT[idx*2] = c;  g_TABT[idx*2+1] = s;
  }
  for (int idx = tid; idx < 256*32; idx += nt) {     // invx premult: e^{+i kx x}
    int x = idx >> 5, kxi = idx & 31;
    int sx = (kxi < 16) ? kxi : kxi + 224;           // -32 mod 256 = 224
    int p = (sx * x) & 255;
    float a = (float)p * TWO_PI_OVER_256;
    float s, c; sincosf(a, &s, &c);
    g_TABX[idx*2] = c;  g_TABX[idx*2+1] = s;
  }
  for (int idx = tid; idx < 256*32; idx += nt) {     // inverse-y twiddles (comb B)
    int y = idx >> 5, kk = idx & 31, k = kk & 15;
    int p = (k * y) & 255;
    float a = (float)p * TWO_PI_OVER_256;
    float s, c; sincosf(a, &s, &c);
    float val = (kk < 16) ? c : -s;
    unsigned short h, l; bfsplit(val, h, l);
    g_TBTH[idx] = h; g_TBTL[idx] = l;
  }
  for (int idx = tid; idx < 16384; idx += nt) {      // fwd-y A-fragment twiddles
    int j = idx & 7, lane = (idx >> 3) & 63, ks = (idx >> 9) & 7;
    int mt = (idx >> 12) & 1, plane = (idx >> 13) & 1;
    int qf = lane >> 4, nf = lane & 15;
    int mode = mt*16 + nf;
    int y = ks*32 + qf*8 + j;
    int p = ((mode & 15) * y) & 255;
    float a = (float)p * TWO_PI_OVER_256;
    float s, c; sincosf(a, &s, &c);
    float val = (mode < 16) ? c : -s;                // e^{-i ky y}: Re=cos, Im=-sin
    unsigned short h, l; bfsplit(val, h, l);
    if (plane == 0) g_TYF[idx] = h; else g_TYF[idx] = l;
  }
  for (int idx = tid; idx < 64*256; idx += nt) {     // fc1_w (64,256) -> [j][c] split
    int j = idx >> 6, c = idx & 63;
    unsigned short h, l; bfsplit(fc1w[c*256 + j], h, l);
    g_FC1TH[idx] = h; g_FC1TL[idx] = l;
  }
  for (int idx = tid; idx < 4*64*64; idx += nt) {    // cw fragments [blk][pl][o][i]
    int blk = idx >> 12, o = (idx >> 6) & 63, i = idx & 63;
    unsigned short h, l; bfsplit(cw[(size_t)blk*4096 + o*64 + i], h, l);
    g_CWF[((size_t)blk*2 + 0)*4096 + o*64 + i] = h;
    g_CWF[((size_t)blk*2 + 1)*4096 + o*64 + i] = l;
  }
}

// ---------------- one-time W transpose: W'[blk][kxi][i][m][o]{re,im}
__global__ __launch_bounds__(256) void k_wt(const float* __restrict__ w1,
                                            const float* __restrict__ w2) {
  __shared__ float ls[64*34];
  int bid = blockIdx.x;
  int blk = bid >> 11, kxi = (bid >> 6) & 31, i = bid & 63;
  int t = threadIdx.x;
  int mx = kxi & 15;
  const float* wsrc = ((kxi < 16) ? w1 : w2)
                      + (size_t)blk*64*64*512 + (size_t)i*32768 + mx*32;
  int o = t >> 2, part = t & 3;
  float4 v0 = *(const float4*)(wsrc + o*512 + part*8);
  float4 v1 = *(const float4*)(wsrc + o*512 + part*8 + 4);
  *(float4*)&ls[o*34 + part*8] = v0;
  *(float4*)&ls[o*34 + part*8 + 4] = v1;
  __syncthreads();
  float* outp = g_WT + (((size_t)blk*32 + kxi)*64 + i)*2048;
  float vals[8];
  #pragma unroll
  for (int j = 0; j < 8; ++j) {
    int idx = t*8 + j;
    int mm = idx >> 7, rem = idx & 127, o2 = rem >> 1, c = rem & 1;
    vals[j] = ls[o2*34 + mm*2 + c];
  }
  *(float4*)&outp[t*8]     = make_float4(vals[0], vals[1], vals[2], vals[3]);
  *(float4*)&outp[t*8 + 4] = make_float4(vals[4], vals[5], vals[6], vals[7]);
}

// ------------- lift (fc0) + FUSED forward y-DFT (single-barrier epilogue)
__global__ __launch_bounds__(256) void k_lift(const float* __restrict__ x,
                                              const float* __restrict__ w,
                                              const float* __restrict__ bias) {
  __shared__ unsigned Lp[64*LPS];     // 66.8 KB packed (hi|lo) h row [c][y]
  int b = blockIdx.x >> 8, xr = blockIdx.x & 255, t = threadIdx.x;  // t = y
  const float* xp = x + ((size_t)(b*256 + xr) * 256) * 3;
  float x0 = xp[t*3], x1 = xp[t*3+1], x2 = xp[t*3+2];
  unsigned short* row = g_H2 + (size_t)(b*256 + xr) * 32768;
  float v[64];
  #pragma unroll
  for (int c = 0; c < 64; ++c)
    v[c] = bias[c] + x0*w[c] + x1*w[64+c] + x2*w[128+c];
  #pragma unroll
  for (int ktc = 0; ktc < 2; ++ktc)
    #pragma unroll
    for (int q8 = 0; q8 < 4; ++q8) {
      short8 hi, lo;
      #pragma unroll
      for (int j = 0; j < 8; ++j) {
        int c = ktc*32 + q8*8 + j;
        unsigned short h, l; bfsplit(v[c], h, l);
        hi[j] = (short)h; lo[j] = (short)l;
        Lp[c*LPS + t] = ((unsigned)h << 16) | l;
      }
      *(short8*)&row[h2f_off(t, ktc*32 + q8*8, 0)] = hi;
      *(short8*)&row[h2f_off(t, ktc*32 + q8*8, 1)] = lo;
    }
  __syncthreads();

  int wv = t >> 6, lane = t & 63, q = lane >> 4, n = lane & 15;
  const float inv = 1.f/65536.f;
  {
    int pf = wv;                              // this wave's c-chunk
    float4v a2[2]; a2[0] = (float4v)(0.f); a2[1] = (float4v)(0.f);
    #pragma unroll
    for (int kg = 0; kg < 8; ++kg) {          // all 8 y-chunks
      short8 bh, bl;
      #pragma unroll
      for (int j = 0; j < 8; ++j) {
        unsigned pv = Lp[(pf*16 + n)*LPS + kg*32 + q*8 + j];
        bh[j] = (short)(pv >> 16); bl[j] = (short)(pv & 0xffffu);
      }
      #pragma unroll
      for (int mt2 = 0; mt2 < 2; ++mt2) {
        short8 ah = *(const short8*)&g_TYF[((0*2 + mt2)*8 + kg)*512 + lane*8];
        short8 al = *(const short8*)&g_TYF[((2 + mt2)*8 + kg)*512 + lane*8];
        a2[mt2] = mfma16(ah, bh, a2[mt2]);
        a2[mt2] = mfma16(ah, bl, a2[mt2]);
        a2[mt2] = mfma16(al, bh, a2[mt2]);
      }
    }
    #pragma unroll
    for (int mt2 = 0; mt2 < 2; ++mt2)
      #pragma unroll
      for (int r = 0; r < 4; ++r) {
        int mode = mt2*16 + q*4 + r;
        g_FY[((size_t)(b*32 + mode)*256 + xr)*64 + pf*16 + n] = a2[mt2][r] * inv;
      }
  }
}

// ------------------- forward x-DFT from FY -> F.  grid 2048: (b16, cg8, ky16)
__global__ __launch_bounds__(256) void k_fwdx() {
  __shared__ float fr[256*8], fi[256*8];
  int bid = blockIdx.x;
  int b = bid >> 7, cg = (bid >> 4) & 7, ky = bid & 15;
  int t = threadIdx.x, kxi = t >> 3, cl = t & 7;
  int kt = (kxi < 16) ? kxi : 32 - kxi;
  float sgn = (kxi < 16) ? -1.f : 1.f;         // e^{-i kx x} = (c, sgn*s)
  {
    int u0 = t, x0 = u0 >> 1, p0 = u0 & 1;
    int u1 = t + 256, x1 = u1 >> 1, p1 = u1 & 1;
    const float* fyr = g_FY + ((size_t)(b*32 + ky)*256)*64 + cg*8;
    const float* fyi = g_FY + ((size_t)(b*32 + 16 + ky)*256)*64 + cg*8;
    *(float4*)&fr[x0*8 + p0*4] = *(const float4*)&fyr[(size_t)x0*64 + p0*4];
    *(float4*)&fr[x1*8 + p1*4] = *(const float4*)&fyr[(size_t)x1*64 + p1*4];
    *(float4*)&fi[x0*8 + p0*4] = *(const float4*)&fyi[(size_t)x0*64 + p0*4];
    *(float4*)&fi[x1*8 + p1*4] = *(const float4*)&fyi[(size_t)x1*64 + p1*4];
  }
  __syncthreads();
  float r0 = 0.f, r1 = 0.f, i0 = 0.f, i1 = 0.f;
  #pragma unroll 2
  for (int x = 0; x < 256; x += 2) {
    float2 tw0 = ((const float2*)g_TABT)[kt*256 + x];
    float2 tw1 = ((const float2*)g_TABT)[kt*256 + x + 1];
    float a0 = fr[x*8 + cl], b0 = fi[x*8 + cl];
    float a1 = fr[(x+1)*8 + cl], b1 = fi[(x+1)*8 + cl];
    float es0 = sgn*tw0.y, es1 = sgn*tw1.y;
    r0 += a0*tw0.x - b0*es0;  i0 += a0*es0 + b0*tw0.x;
    r1 += a1*tw1.x - b1*es1;  i1 += a1*es1 + b1*tw1.x;
  }
  ((float2*)g_F)[((size_t)(kxi*16 + b)*64 + cg*8 + cl)*16 + ky] =
    make_float2(r0 + r1, i0 + i1);
}

// ---------------------------------------------------- spectral channel mix
// mix3: W-row register reuse. grid 256 (kxi 32, bq 4, mh 2).
__global__ __launch_bounds__(256) void k_mix3(int blk) {
  __shared__ float2 Lr[4*4*8*64];    // [w][b][m][o] 64KB
  int bid = blockIdx.x;
  int kxi = bid >> 3, bq = (bid >> 1) & 3, mh = bid & 1;
  int t = threadIdx.x;
  int o = t & 63;
  int w = __builtin_amdgcn_readfirstlane((int)(t >> 6));
  const float2* Wp = (const float2*)g_WT + (((size_t)blk*32 + kxi)*64)*1024 + mh*8*64 + o;
  const float2* Fb = (const float2*)g_F + ((size_t)kxi*16 + bq*4)*64*16 + mh*8;

  float gr[4][8], gi[4][8];
  #pragma unroll
  for (int b = 0; b < 4; ++b)
    #pragma unroll
    for (int m = 0; m < 8; ++m) { gr[b][m] = 0.f; gi[b][m] = 0.f; }

  for (int il = 0; il < 16; ++il) {
    int i = w*16 + il;
    const float2* wrow = Wp + (size_t)i*1024;       // [m][o]
    float2 wv[8];
    #pragma unroll
    for (int m = 0; m < 8; ++m) wv[m] = wrow[(size_t)m*64];
    #pragma unroll
    for (int b = 0; b < 4; ++b) {
      const float2* fr2 = Fb + ((size_t)b*64 + i)*16;  // uniform -> s_load
      #pragma unroll
      for (int m = 0; m < 8; ++m) {
        float2 f = fr2[m];
        gr[b][m] += f.x*wv[m].x - f.y*wv[m].y;
        gi[b][m] += f.x*wv[m].y + f.y*wv[m].x;
      }
    }
  }
  #pragma unroll
  for (int b = 0; b < 4; ++b)
    #pragma unroll
    for (int m = 0; m < 8; ++m)
      Lr[((w*4 + b)*8 + m)*64 + o] = make_float2(gr[b][m], gi[b][m]);
  __syncthreads();
  for (int e = t; e < 2048; e += 256) {
    int oo = e & 63, m = (e >> 6) & 7, b = e >> 9;
    float2 s0 = Lr[((0*4 + b)*8 + m)*64 + oo];
    float2 s1 = Lr[((1*4 + b)*8 + m)*64 + oo];
    float2 s2 = Lr[((2*4 + b)*8 + m)*64 + oo];
    float2 s3 = Lr[((3*4 + b)*8 + m)*64 + oo];
    float2 g = make_float2((s0.x + s1.x) + (s2.x + s3.x),
                           (s0.y + s1.y) + (s2.y + s3.y));
    ((float2*)g_G)[((size_t)(bq*4 + b)*512 + kxi*16 + mh*8 + m)*64 + oo] = g;
  }
}

// ------------------- inverse-x DFT hoisted out of combine.
// grid 512: (b 16, xc 32), 512 threads; each block does 8 xr rows.
__global__ __launch_bounds__(512) void k_invx() {
  __shared__ float2 Tw[256];        // 8 xr x 32 kxi twiddles
  __shared__ float  Tr[8*64*33];    // 67.6 KB: all 8 xr transposes at once
  int bid = blockIdx.x;
  int b = bid >> 5, xc = bid & 31;
  int t = threadIdx.x;
  if (t < 256) Tw[t] = ((const float2*)g_TABX)[(size_t)(xc*8)*32 + t];
  int o2 = t & 31, k = t >> 5;       // o = 2*o2, 2*o2+1 ; k = 0..15
  const float4* Gb4 = (const float4*)g_G + (size_t)b*512*32;
  float4 acc[8];
  #pragma unroll
  for (int r = 0; r < 8; ++r) acc[r] = make_float4(0.f, 0.f, 0.f, 0.f);
  __syncthreads();
  for (int kxi = 0; kxi < 32; ++kxi) {
    float4 g = Gb4[(size_t)(kxi*16 + k)*32 + o2];
    #pragma unroll
    for (int r = 0; r < 8; ++r) {
      float2 tw = Tw[r*32 + kxi];
      acc[r].x += g.x*tw.x - g.y*tw.y;
      acc[r].y += g.x*tw.y + g.y*tw.x;
      acc[r].z += g.z*tw.x - g.w*tw.y;
      acc[r].w += g.z*tw.y + g.w*tw.x;
    }
  }
  float wk = k ? 2.f : 1.f;                    // irfft: ky=0 once, others x2
  #pragma unroll
  for (int r = 0; r < 8; ++r) {
    float* Trr = &Tr[r*2112];
    Trr[(2*o2)*33 + k]        = wk*acc[r].x;   // re -> col k
    Trr[(2*o2)*33 + 16 + k]   = wk*acc[r].y;   // im -> col 16+k
    Trr[(2*o2+1)*33 + k]      = wk*acc[r].z;
    Trr[(2*o2+1)*33 + 16 + k] = wk*acc[r].w;
  }
  __syncthreads();
  int o = t >> 3, c0 = (t & 7)*4;
  #pragma unroll
  for (int r = 0; r < 8; ++r) {
    unsigned long long hv = 0, lv = 0;
    #pragma unroll
    for (int j = 0; j < 4; ++j) {
      unsigned short h, l; bfsplit(Tr[r*2112 + o*33 + c0 + j], h, l);
      hv |= (unsigned long long)h << (16*j);
      lv |= (unsigned long long)l << (16*j);
    }
    unsigned short* dst = g_AS + (size_t)(b*256 + xc*8 + r)*4096 + o*32 + c0;
    *(unsigned long long*)&dst[0]    = hv;     // hi plane
    *(unsigned long long*)&dst[2048] = lv;     // lo plane
  }
}

// ------------------- combine (blk 0..2): C(64o x 256y) = A(64x96) B(96x256)
// 512 threads / 8 waves; wave (yq, oh) owns 64y x 32o tile.
// R6 structure (best verified): full 64KB pool staged once under kt0,
// single-phase epilogue (full 64-row Lp aliasing dead pool), per-wave fy.
__global__ __launch_bounds__(512, 4) void k_comb(int blk, const float* __restrict__ cb) {
  __shared__ unsigned Lp[64*LPS];               // 66.8 KB; first 64KB = stage pool
  unsigned short* pool = (unsigned short*)Lp;
  int b = blockIdx.x >> 8, xr = blockIdx.x & 255;
  int t = threadIdx.x;
  unsigned short* row = g_H2 + (size_t)(b*256 + xr) * 32768;
  int w = t >> 6, lane = t & 63, q = lane >> 4, n = lane & 15;
  int yq = w >> 1, oh = w & 1;
  int ybase = yq*64;
  const unsigned short* Ab = g_AS + (size_t)(b*256 + xr)*4096;
  const unsigned short* Cw = g_CWF + (size_t)blk*8192;

  float4v acc[4][2];
  #pragma unroll
  for (int nt = 0; nt < 4; ++nt)
    #pragma unroll
    for (int mtl = 0; mtl < 2; ++mtl) acc[nt][mtl] = (float4v)(0.f);

  // kt0 + cw register loads first (their wait leaves staging in flight)
  short8 af0[2][2], af1[2][2], af2[2][2], b0h[4], b0l[4];
  #pragma unroll
  for (int mtl = 0; mtl < 2; ++mtl) {
    int o = (oh*2 + mtl)*16 + n;
    af0[mtl][0] = *(const short8*)&Ab[o*32 + q*8];
    af0[mtl][1] = *(const short8*)&Ab[2048 + o*32 + q*8];
    af1[mtl][0] = *(const short8*)&Cw[o*64 + q*8];
    af1[mtl][1] = *(const short8*)&Cw[4096 + o*64 + q*8];
    af2[mtl][0] = *(const short8*)&Cw[o*64 + 32 + q*8];
    af2[mtl][1] = *(const short8*)&Cw[4096 + o*64 + 32 + q*8];
  }
  #pragma unroll
  for (int nt = 0; nt < 4; ++nt) {
    int y = ybase + nt*16 + n;
    b0h[nt] = *(const short8*)&g_TBTH[y*32 + q*8];
    b0l[nt] = *(const short8*)&g_TBTL[y*32 + q*8];
  }
  // async-stage the full H2 row: wave w -> stripes 8w..8w+7 (1KB each)
  #pragma unroll
  for (int i = 0; i < 8; ++i) {
    int s = w*8 + i;
    gl_lds16(row + s*512 + lane*8, &pool[s*512]);
  }
  // kt0 compute (staged loads still in flight behind it)
  #pragma unroll
  for (int nt = 0; nt < 4; ++nt)
    #pragma unroll
    for (int mtl = 0; mtl < 2; ++mtl) {
      acc[nt][mtl] = mfma16(af0[mtl][0], b0h[nt], acc[nt][mtl]);
      acc[nt][mtl] = mfma16(af0[mtl][0], b0l[nt], acc[nt][mtl]);
      acc[nt][mtl] = mfma16(af0[mtl][1], b0h[nt], acc[nt][mtl]);
    }
  __syncthreads();   // drains vmcnt: all 64 stripes resident in LDS

  // kt1/kt2 B-fragments from LDS: stripe = ytile*4 + (kt-1)*2 + plane
  #pragma unroll
  for (int nt = 0; nt < 4; ++nt) {
    int sb = (yq*4 + nt)*4;
    short8 p1h = *(const short8*)&pool[(sb + 0)*512 + lane*8];
    short8 p1l = *(const short8*)&pool[(sb + 1)*512 + lane*8];
    short8 p2h = *(const short8*)&pool[(sb + 2)*512 + lane*8];
    short8 p2l = *(const short8*)&pool[(sb + 3)*512 + lane*8];
    #pragma unroll
    for (int mtl = 0; mtl < 2; ++mtl) {
      acc[nt][mtl] = mfma16(af1[mtl][0], p1h, acc[nt][mtl]);
      acc[nt][mtl] = mfma16(af1[mtl][0], p1l, acc[nt][mtl]);
      acc[nt][mtl] = mfma16(af1[mtl][1], p1h, acc[nt][mtl]);
      acc[nt][mtl] = mfma16(af2[mtl][0], p2h, acc[nt][mtl]);
      acc[nt][mtl] = mfma16(af2[mtl][0], p2l, acc[nt][mtl]);
      acc[nt][mtl] = mfma16(af2[mtl][1], p2h, acc[nt][mtl]);
    }
  }
  __syncthreads();   // all pool reads done; pool dead -> Lp may overwrite

  // ---- single-phase epilogue: relu+bias+pack; full Lp + direct H2F stores
  #pragma unroll
  for (int mtl = 0; mtl < 2; ++mtl) {
    int p = oh*2 + mtl;
    float4v cbv = *(const float4v*)(cb + p*16 + q*4);
    #pragma unroll
    for (int nt = 0; nt < 4; ++nt) {
      int y = ybase + nt*16 + n;
      unsigned long long hh = 0, ll = 0;
      #pragma unroll
      for (int r = 0; r < 4; ++r) {
        float v = fmaxf(acc[nt][mtl][r] + cbv[r], 0.f);
        unsigned short h, l; bfsplit(v, h, l);
        hh |= (unsigned long long)h << (r*16);
        ll |= (unsigned long long)l << (r*16);
        Lp[(p*16 + q*4 + r)*LPS + y] = ((unsigned)h << 16) | l;
      }
      int off0 = (((yq*4 + nt)*2 + (p>>1))*2 + 0)*512
               + (2*(p&1) + (q>>1))*128 + n*8 + 4*(q&1);
      *(unsigned long long*)&row[off0]       = hh;
      *(unsigned long long*)&row[off0 + 512] = ll;
    }
  }
  __syncthreads();                              // Lp complete

  // ---- fy DFT: wave w owns (mt2 = w&1, c-chunk pf = w>>1); 24 MFMAs, no reduce
  {
    const float inv = 1.f/65536.f;
    int mt2 = w & 1, pf = w >> 1;
    float4v a2 = (float4v)(0.f);
    #pragma unroll
    for (int kg = 0; kg < 8; ++kg) {
      short8 bh, bl;
      #pragma unroll
      for (int j = 0; j < 8; ++j) {
        unsigned pv = Lp[(pf*16 + n)*LPS + kg*32 + q*8 + j];
        bh[j] = (short)(pv >> 16); bl[j] = (short)(pv & 0xffffu);
      }
      short8 ah = *(const short8*)&g_TYF[((0*2 + mt2)*8 + kg)*512 + lane*8];
      short8 al = *(const short8*)&g_TYF[((2 + mt2)*8 + kg)*512 + lane*8];
      a2 = mfma16(ah, bh, a2);
      a2 = mfma16(ah, bl, a2);
      a2 = mfma16(al, bh, a2);
    }
    #pragma unroll
    for (int r = 0; r < 4; ++r) {
      int mode = mt2*16 + q*4 + r;
      g_FY[((size_t)(b*32 + mode)*256 + xr)*64 + pf*16 + n] = a2[r] * inv;
    }
  }
}

// ------------------- combine blk 3 + FUSED head (R6 version: 67KB pool,
// single-pass Lp, (512,4) -> no spill; head phase needs ~100 live regs).
__global__ __launch_bounds__(512, 4) void k_combh(const float* __restrict__ cb,
                                               const float* __restrict__ fc1b,
                                               const float* __restrict__ fc2w,
                                               const float* __restrict__ fc2b,
                                               float* __restrict__ out) {
  __shared__ unsigned Lp[64*LPS];               // 66.8 KB; first 64KB = stage pool
  unsigned short* pool = (unsigned short*)Lp;
  int b = blockIdx.x >> 8, xr = blockIdx.x & 255;
  int t = threadIdx.x;
  unsigned short* row = g_H2 + (size_t)(b*256 + xr) * 32768;
  int w = t >> 6, lane = t & 63, q = lane >> 4, n = lane & 15;
  int yq = w >> 1, oh = w & 1;
  int ybase = yq*64;
  const unsigned short* Ab = g_AS + (size_t)(b*256 + xr)*4096;
  const unsigned short* Cw = g_CWF + (size_t)3*8192;

  float4v acc[4][2];
  #pragma unroll
  for (int nt = 0; nt < 4; ++nt)
    #pragma unroll
    for (int mtl = 0; mtl < 2; ++mtl) acc[nt][mtl] = (float4v)(0.f);

  short8 af0[2][2], af1[2][2], af2[2][2], b0h[4], b0l[4];
  #pragma unroll
  for (int mtl = 0; mtl < 2; ++mtl) {
    int o = (oh*2 + mtl)*16 + n;
    af0[mtl][0] = *(const short8*)&Ab[o*32 + q*8];
    af0[mtl][1] = *(const short8*)&Ab[2048 + o*32 + q*8];
    af1[mtl][0] = *(const short8*)&Cw[o*64 + q*8];
    af1[mtl][1] = *(const short8*)&Cw[4096 + o*64 + q*8];
    af2[mtl][0] = *(const short8*)&Cw[o*64 + 32 + q*8];
    af2[mtl][1] = *(const short8*)&Cw[4096 + o*64 + 32 + q*8];
  }
  #pragma unroll
  for (int nt = 0; nt < 4; ++nt) {
    int y = ybase + nt*16 + n;
    b0h[nt] = *(const short8*)&g_TBTH[y*32 + q*8];
    b0l[nt] = *(const short8*)&g_TBTL[y*32 + q*8];
  }
  #pragma unroll
  for (int i = 0; i < 8; ++i) {
    int s = w*8 + i;
    gl_lds16(row + s*512 + lane*8, &pool[s*512]);
  }
  #pragma unroll
  for (int nt = 0; nt < 4; ++nt)
    #pragma unroll
    for (int mtl = 0; mtl < 2; ++mtl) {
      acc[nt][mtl] = mfma16(af0[mtl][0], b0h[nt], acc[nt][mtl]);
      acc[nt][mtl] = mfma16(af0[mtl][0], b0l[nt], acc[nt][mtl]);
      acc[nt][mtl] = mfma16(af0[mtl][1], b0h[nt], acc[nt][mtl]);
    }
  __syncthreads();   // stage resident

  #pragma unroll
  for (int nt = 0; nt < 4; ++nt) {
    int sb = (yq*4 + nt)*4;
    short8 p1h = *(const short8*)&pool[(sb + 0)*512 + lane*8];
    short8 p1l = *(const short8*)&pool[(sb + 1)*512 + lane*8];
    short8 p2h = *(const short8*)&pool[(sb + 2)*512 + lane*8];
    short8 p2l = *(const short8*)&pool[(sb + 3)*512 + lane*8];
    #pragma unroll
    for (int mtl = 0; mtl < 2; ++mtl) {
      acc[nt][mtl] = mfma16(af1[mtl][0], p1h, acc[nt][mtl]);
      acc[nt][mtl] = mfma16(af1[mtl][0], p1l, acc[nt][mtl]);
      acc[nt][mtl] = mfma16(af1[mtl][1], p1h, acc[nt][mtl]);
      acc[nt][mtl] = mfma16(af2[mtl][0], p2h, acc[nt][mtl]);
      acc[nt][mtl] = mfma16(af2[mtl][0], p2l, acc[nt][mtl]);
      acc[nt][mtl] = mfma16(af2[mtl][1], p2h, acc[nt][mtl]);
    }
  }
  __syncthreads();   // pool reads done; pool dead -> Lp may overwrite

  // ---- single-phase Lp write: h (+cb, NO relu) for all channels
  #pragma unroll
  for (int mtl = 0; mtl < 2; ++mtl) {
    int p = oh*2 + mtl;
    float4v cbv = *(const float4v*)(cb + p*16 + q*4);
    #pragma unroll
    for (int nt = 0; nt < 4; ++nt) {
      int y = ybase + nt*16 + n;
      #pragma unroll
      for (int r = 0; r < 4; ++r) {
        float v = acc[nt][mtl][r] + cbv[r];
        unsigned short h, l; bfsplit(v, h, l);
        Lp[(p*16 + q*4 + r)*LPS + y] = ((unsigned)h << 16) | l;
      }
    }
  }
  __syncthreads();                              // Lp complete

  // ---- captures from full Lp (c = q*8+j and 32 + q*8+j)
  short8 B0h[4], B0l[4], B1h[4], B1l[4];
  #pragma unroll
  for (int ntl = 0; ntl < 4; ++ntl) {
    int y = ybase + ntl*16 + n;
    #pragma unroll
    for (int j = 0; j < 8; ++j) {
      unsigned pv0 = Lp[(q*8 + j)*LPS + y];
      B0h[ntl][j] = (short)(pv0 >> 16); B0l[ntl][j] = (short)(pv0 & 0xffffu);
      unsigned pv1 = Lp[(32 + q*8 + j)*LPS + y];
      B1h[ntl][j] = (short)(pv1 >> 16); B1l[ntl][j] = (short)(pv1 & 0xffffu);
    }
  }

  // ---- head GEMM: this wave's j-half (oh), from captured fragments
  float outp[4] = {0.f, 0.f, 0.f, 0.f};
  #pragma unroll 2
  for (int mti = 0; mti < 8; ++mti) {
    int mt = oh*8 + mti;
    int jrow = mt*16 + n;
    short8 a0h = *(const short8*)&g_FC1TH[jrow*64 + q*8];
    short8 a0l = *(const short8*)&g_FC1TL[jrow*64 + q*8];
    short8 a1h = *(const short8*)&g_FC1TH[jrow*64 + 32 + q*8];
    short8 a1l = *(const short8*)&g_FC1TL[jrow*64 + 32 + q*8];
    float4v ac2[4];
    #pragma unroll
    for (int ntl = 0; ntl < 4; ++ntl) ac2[ntl] = (float4v)(0.f);
    #pragma unroll
    for (int ntl = 0; ntl < 4; ++ntl) {
      ac2[ntl] = mfma16(a0h, B0h[ntl], ac2[ntl]);
      ac2[ntl] = mfma16(a0h, B0l[ntl], ac2[ntl]);
      ac2[ntl] = mfma16(a0l, B0h[ntl], ac2[ntl]);
      ac2[ntl] = mfma16(a1h, B1h[ntl], ac2[ntl]);
      ac2[ntl] = mfma16(a1h, B1l[ntl], ac2[ntl]);
      ac2[ntl] = mfma16(a1l, B1h[ntl], ac2[ntl]);
    }
    float4v b1 = *(const float4v*)(fc1b + mt*16 + q*4);
    float4v w2 = *(const float4v*)(fc2w + mt*16 + q*4);
    #pragma unroll
    for (int ntl = 0; ntl < 4; ++ntl)
      #pragma unroll
      for (int r = 0; r < 4; ++r)
        outp[ntl] += w2[r] * fmaxf(ac2[ntl][r] + b1[r], 0.f);
  }

  // intra-wave j-reduce (over q), then cross-wave (oh pair) via LDS
  float vv[4];
  #pragma unroll
  for (int ntl = 0; ntl < 4; ++ntl) {
    float v = outp[ntl];
    v += __shfl_xor(v, 16);
    v += __shfl_xor(v, 32);
    vv[ntl] = v;
  }
  float* Ored = (float*)Lp;                     // reuse LDS (captures done)
  __syncthreads();
  if (oh == 0 && q == 0) {
    #pragma unroll
    for (int ntl = 0; ntl < 4; ++ntl)
      Ored[ybase + ntl*16 + n] = vv[ntl];
  }
  __syncthreads();
  if (oh == 1 && q == 0) {
    float bias2 = fc2b[0];
    #pragma unroll
    for (int ntl = 0; ntl < 4; ++ntl) {
      int y = ybase + ntl*16 + n;
      out[((size_t)(b*256 + xr))*256 + y] = Ored[y] + vv[ntl] + bias2;
    }
  }
}

// ----------------------------------------------------------------- launcher
extern "C" void kernel_launch(void* const* d_in, const int* in_sizes, int n_in,
                              void* d_out, int out_size, void* d_ws, size_t ws_size,
                              hipStream_t stream) {
  (void)in_sizes; (void)n_in; (void)out_size; (void)d_ws; (void)ws_size;
  const float* x    = (const float*)d_in[0];
  const float* fc0w = (const float*)d_in[1];
  const float* fc0b = (const float*)d_in[2];
  const float* w1   = (const float*)d_in[3];
  const float* w2   = (const float*)d_in[4];
  const float* cw   = (const float*)d_in[5];
  const float* cb   = (const float*)d_in[6];
  const float* fc1w = (const float*)d_in[7];
  const float* fc1b = (const float*)d_in[8];
  const float* fc2w = (const float*)d_in[9];
  const float* fc2b = (const float*)d_in[10];
  float* out = (float*)d_out;

  hipLaunchKernelGGL(k_init, dim3(64),   dim3(256), 0, stream, fc1w, cw);
  hipLaunchKernelGGL(k_wt,   dim3(8192), dim3(256), 0, stream, w1, w2);
  hipLaunchKernelGGL(k_lift, dim3(4096), dim3(256), 0, stream, x, fc0w, fc0b);
  for (int blk = 0; blk < 3; ++blk) {
    hipLaunchKernelGGL(k_fwdx, dim3(2048), dim3(256), 0, stream);
    hipLaunchKernelGGL(k_mix3, dim3(256),  dim3(256), 0, stream, blk);
    hipLaunchKernelGGL(k_invx, dim3(512),  dim3(512), 0, stream);
    hipLaunchKernelGGL(k_comb, dim3(4096), dim3(512), 0, stream,
                       blk, cb + (size_t)blk*64);
  }
  hipLaunchKernelGGL(k_fwdx, dim3(2048), dim3(256), 0, stream);
  hipLaunchKernelGGL(k_mix3, dim3(256),  dim3(256), 0, stream, 3);
  hipLaunchKernelGGL(k_invx, dim3(512),  dim3(512), 0, stream);
  hipLaunchKernelGGL(k_combh, dim3(4096), dim3(512), 0, stream,
                     cb + (size_t)3*64, fc1b, fc2w, fc2b, out);
}